// Round 6
// baseline (1138.900 us; speedup 1.0000x reference)
//
#include <hip/hip_runtime.h>
#include <hip/hip_bf16.h>
#include <cstdint>
#include <cstddef>

// ---------- types ----------
typedef short bf16x8 __attribute__((ext_vector_type(8)));   // 8 bf16 in 4 VGPRs
typedef float f32x4 __attribute__((ext_vector_type(4)));

// GEMM geometry: 256x128 tile, BK=64, 8 waves (4M x 2N), NBUF=3 ring.
#define BM 256
#define BN 128
#define BK 64

// async global->LDS, 16B per lane (used for L2-resident weights only).
__device__ __forceinline__ void gl_lds16(const __hip_bfloat16* gp, __hip_bfloat16* lp) {
  __builtin_amdgcn_global_load_lds((const __attribute__((address_space(1))) void*)gp,
                                   (__attribute__((address_space(3))) void*)lp, 16, 0, 0);
}

// ---------- weight transpose + bf16 convert: dst[c*R + r] = src[r*C + c] ----------
__global__ void __launch_bounds__(256) wtrans_kernel(const float* __restrict__ src,
                                                     __hip_bfloat16* __restrict__ dst,
                                                     int R, int C) {
  int idx = blockIdx.x * 256 + threadIdx.x;
  if (idx >= R * C) return;
  int r = idx / C, c = idx % C;
  dst[(size_t)c * R + r] = __float2bfloat16(src[idx]);
}

// ---------- per-row sort: one WAVE per row, fully in-register bitonic ----------
__global__ void __launch_bounds__(256) sort_kernel(const float* __restrict__ x,
                                                   __hip_bfloat16* __restrict__ h0) {
  int row = blockIdx.x * 4 + (threadIdx.x >> 6);
  int lane = threadIdx.x & 63;
  const float* xr = x + (size_t)row * 512;

  float v[8];
  *(float4*)&v[0] = *(const float4*)&xr[lane * 8];
  *(float4*)&v[4] = *(const float4*)&xr[lane * 8 + 4];

  __hip_bfloat16* h = h0 + (size_t)row * 1024;
  {
    alignas(16) __hip_bfloat16 ob[8];
#pragma unroll
    for (int i = 0; i < 8; ++i) ob[i] = __float2bfloat16(v[i]);
    *(bf16x8*)&h[lane * 8] = *(const bf16x8*)ob;
  }

#pragma unroll
  for (int k = 2; k <= 512; k <<= 1) {
#pragma unroll
    for (int j = k >> 1; j > 0; j >>= 1) {
      if (j >= 8) {
        int L = j >> 3;
        bool lower = (lane & L) == 0;
        bool up = (((lane * 8) & k) == 0);
        bool sel = (lower == up);
#pragma unroll
        for (int r = 0; r < 8; ++r) {
          float pv = __shfl_xor(v[r], L, 64);
          float mn = fminf(v[r], pv), mx = fmaxf(v[r], pv);
          v[r] = sel ? mn : mx;
        }
      } else {
#pragma unroll
        for (int r = 0; r < 8; ++r) {
          if ((r & j) == 0) {
            int r2 = r | j;
            bool up = ((((lane * 8) + r) & k) == 0);
            float a = v[r], b = v[r2];
            float mn = fminf(a, b), mx = fmaxf(a, b);
            v[r] = up ? mn : mx;
            v[r2] = up ? mx : mn;
          }
        }
      }
    }
  }

  {
    alignas(16) __hip_bfloat16 ob[8];
#pragma unroll
    for (int i = 0; i < 8; ++i) ob[i] = __float2bfloat16(v[i]);
    *(bf16x8*)&h[512 + lane * 8] = *(const bf16x8*)ob;
  }
}

// ---------- GEMM: C(M,N) = A(M,K) @ BT(N,K)^T, bf16 in, f32 accum ----------
// A (HBM stream): reg-staged — global_load_dwordx4 -> VGPR ring (3 tiles) ->
//   swizzled ds_write_b128. Deep in-flight on the normal VMEM path (no
//   gl_lds DMA-queue cap). Loaded 4 iters before ds_read, 2 before ds_write.
// B (L2-resident weights): gl_lds direct with pre-swizzled global source.
// Per-wave vmcnt ledger (issue order per iter: B(t+2), A(t+4)):
//   end-of-iter-t wait keeps {B(t+2):2, A(t+4):4} -> vmcnt(6); completes
//   B(t+1) (read at t+1) and A(t+3) (ds_written at t+1). Tail: 6 -> 2 -> 0.
// EPI: 1 = perm-scatter after G1; 2 = perm-scatter after G2; 3 = relu store;
//      4 = sigmoid(acc) * x, f32 store.
template <int EPI, int N, int K>
__global__ void __launch_bounds__(512) gemm_k(const __hip_bfloat16* __restrict__ A,
                                              const __hip_bfloat16* __restrict__ BT,
                                              __hip_bfloat16* __restrict__ Cb,
                                              float* __restrict__ Co,
                                              const float* __restrict__ X) {
  __shared__ __hip_bfloat16 lA[3][BM * BK];  // 3 x 32 KB
  __shared__ __hip_bfloat16 lB[3][BN * BK];  // 3 x 16 KB   (total 144 KB)

  // bijective XCD swizzle (grid divisible by 8)
  int nwg = gridDim.x;
  int bid = blockIdx.x;
  int cpx = nwg >> 3;
  int wg = (bid & 7) * cpx + (bid >> 3);

  constexpr int NTN = N / BN;
  int m0 = (wg / NTN) * BM;
  int n0 = (wg % NTN) * BN;

  int tid = threadIdx.x;
  int lane = tid & 63;
  int w = tid >> 6;        // 0..7
  int wr = w >> 1;         // 0..3 : wave's 64-row band
  int wc = w & 1;          // 0..1 : wave's 64-col band
  int r16 = lane & 15;
  int g4 = lane >> 4;      // 0..3

  // ---- A reg-staging geometry (linear global; swizzle applied on ds_write) ----
  int lr = lane >> 3;                 // 0..7 : row within 8-row chunk
  int lc = (lane & 7) * 8;            // 0..56 : logical col start (elems)
  int wcol = 8 * ((lane & 7) ^ lr);   // swizzled col start for ds_write
  const __hip_bfloat16* Ag = A + (size_t)(m0 + w * 32 + lr) * K + lc;

  // ---- B staging (gl_lds, pre-swizzled global source) ----
  int acs = 8 * ((lane & 7) ^ lr);
  const __hip_bfloat16* Bsrc = BT + (size_t)(n0 + w * 16 + lr) * K + acs;

  // ---- fragment read offsets (elems), swizzled ----
  int xorr = (r16 & 7) * 8;
  int arow[4], brow[4];
#pragma unroll
  for (int i = 0; i < 4; ++i) arow[i] = (wr * 64 + 16 * i + r16) * BK;
#pragma unroll
  for (int j = 0; j < 4; ++j) brow[j] = (wc * 64 + 16 * j + r16) * BK;
  int kx0 = (g4 * 8) ^ xorr;          // ks=0
  int kx1 = (32 + g4 * 8) ^ xorr;     // ks=1

  f32x4 acc[4][4] = {};
  bf16x8 ra[3][4];   // A reg ring: ra[t%3] holds tile t's 4 chunks (static idx)

#define LOADA(tt)                                                       \
  do {                                                                  \
    const int k0_ = (tt) * BK, b_ = (tt) % 3;                           \
    ra[b_][0] = *(const bf16x8*)(Ag + k0_);                             \
    ra[b_][1] = *(const bf16x8*)(Ag + (size_t)8 * K + k0_);             \
    ra[b_][2] = *(const bf16x8*)(Ag + (size_t)16 * K + k0_);            \
    ra[b_][3] = *(const bf16x8*)(Ag + (size_t)24 * K + k0_);            \
  } while (0)

#define WRITEA(tt)                                                      \
  do {                                                                  \
    const int b_ = (tt) % 3;                                            \
    *(bf16x8*)&lA[b_][(w * 32 + 0 + lr) * BK + wcol] = ra[b_][0];       \
    *(bf16x8*)&lA[b_][(w * 32 + 8 + lr) * BK + wcol] = ra[b_][1];       \
    *(bf16x8*)&lA[b_][(w * 32 + 16 + lr) * BK + wcol] = ra[b_][2];      \
    *(bf16x8*)&lA[b_][(w * 32 + 24 + lr) * BK + wcol] = ra[b_][3];      \
  } while (0)

#define STAGEB(tt)                                                      \
  do {                                                                  \
    const int k0_ = (tt) * BK, b_ = (tt) % 3;                           \
    gl_lds16(Bsrc + k0_, &lB[b_][(w * 2 + 0) * 512]);                   \
    gl_lds16(Bsrc + (size_t)8 * K + k0_, &lB[b_][(w * 2 + 1) * 512]);   \
  } while (0)

  constexpr int NT = K / BK;  // 4, 8, or 16
  // prologue (issue order: A0,A1,A2,B0,B1, then A3)
  LOADA(0); LOADA(1); LOADA(2);
  STAGEB(0); STAGEB(1);
  asm volatile("s_waitcnt vmcnt(8)" ::: "memory");   // A0,A1 done (keep A2,B0,B1)
  WRITEA(0); WRITEA(1);
  LOADA(3);
  asm volatile("s_waitcnt vmcnt(6)" ::: "memory");   // B0,A2 done (keep B1,A3)
  asm volatile("s_waitcnt lgkmcnt(0)" ::: "memory");
  __builtin_amdgcn_s_barrier();

#pragma unroll
  for (int t = 0; t < NT; ++t) {
    const int cur = t % 3;

    if (t + 2 < NT) STAGEB(t + 2);   // -> buf[(t+2)%3], freed at end of t-1
    if (t + 4 < NT) LOADA(t + 4);    // -> ra[(t+1)%3], freed (A(t+1) written at t-1)
    if (t + 2 < NT) WRITEA(t + 2);   // regs done via end-of-(t-1) vmcnt

    // ks = 0 fragments
    bf16x8 a0[4], b0[4];
#pragma unroll
    for (int i = 0; i < 4; ++i) a0[i] = *(const bf16x8*)&lA[cur][arow[i] + kx0];
#pragma unroll
    for (int j = 0; j < 4; ++j) b0[j] = *(const bf16x8*)&lB[cur][brow[j] + kx0];

    __builtin_amdgcn_s_setprio(1);
#pragma unroll
    for (int i = 0; i < 4; ++i)
#pragma unroll
      for (int j = 0; j < 4; ++j)
        acc[i][j] = __builtin_amdgcn_mfma_f32_16x16x32_bf16(a0[i], b0[j], acc[i][j], 0, 0, 0);
    __builtin_amdgcn_s_setprio(0);

    // ks = 1 fragments
    bf16x8 a1[4], b1[4];
#pragma unroll
    for (int i = 0; i < 4; ++i) a1[i] = *(const bf16x8*)&lA[cur][arow[i] + kx1];
#pragma unroll
    for (int j = 0; j < 4; ++j) b1[j] = *(const bf16x8*)&lB[cur][brow[j] + kx1];

    __builtin_amdgcn_s_setprio(1);
#pragma unroll
    for (int i = 0; i < 4; ++i)
#pragma unroll
      for (int j = 0; j < 4; ++j)
        acc[i][j] = __builtin_amdgcn_mfma_f32_16x16x32_bf16(a1[i], b1[j], acc[i][j], 0, 0, 0);
    __builtin_amdgcn_s_setprio(0);

    if (t + 1 < NT) {
      // complete B(t+1) (read next iter) and A(t+3) (written next iter);
      // keep {B(t+2), A(t+4)} in flight.
      if (t + 4 < NT)      asm volatile("s_waitcnt vmcnt(6)" ::: "memory");
      else if (t + 2 < NT) asm volatile("s_waitcnt vmcnt(2)" ::: "memory");
      else                 asm volatile("s_waitcnt vmcnt(0)" ::: "memory");
      asm volatile("s_waitcnt lgkmcnt(0)" ::: "memory");
      __builtin_amdgcn_s_barrier();
    }
  }
#undef LOADA
#undef WRITEA
#undef STAGEB

  // epilogue: D row = g4*4 + r, col = r16 within each 16x16 frag (m89 layout)
#pragma unroll
  for (int i = 0; i < 4; ++i) {
    int grow_base = m0 + wr * 64 + 16 * i + g4 * 4;
#pragma unroll
    for (int j = 0; j < 4; ++j) {
      int gcol = n0 + wc * 64 + 16 * j + r16;
#pragma unroll
      for (int r = 0; r < 4; ++r) {
        int grow = grow_base + r;
        float v = acc[i][j][r];
        if constexpr (EPI == 1) {
          // v0 index j0 = p*512 + n -> dst col = 4*(n&255) + 2p + (n>>8)
          int b = grow >> 1, p = grow & 1;
          Cb[(size_t)b * 1024 + 4 * (gcol & 255) + (p << 1) + (gcol >> 8)] = __float2bfloat16(v);
        } else if constexpr (EPI == 2) {
          // h2 flat j0 = g*256 + n -> dst col = 4*n + g
          int b = grow >> 2, g = grow & 3;
          Cb[(size_t)b * 1024 + 4 * gcol + g] = __float2bfloat16(v);
        } else if constexpr (EPI == 3) {
          Cb[(size_t)grow * N + gcol] = __float2bfloat16(fmaxf(v, 0.f));
        } else {
          float xv = X[(size_t)grow * N + gcol];
          Co[(size_t)grow * N + gcol] = xv / (1.f + __expf(-v));
        }
      }
    }
  }
}

// ---------- launch ----------
extern "C" void kernel_launch(void* const* d_in, const int* in_sizes, int n_in,
                              void* d_out, int out_size, void* d_ws, size_t ws_size,
                              hipStream_t stream) {
  const float* x  = (const float*)d_in[0];
  const float* W1 = (const float*)d_in[1];
  const float* W2 = (const float*)d_in[2];
  const float* W3 = (const float*)d_in[3];
  const float* W4 = (const float*)d_in[4];

  const int B = 131072;

  char* ws = (char*)d_ws;
  __hip_bfloat16* W1T = (__hip_bfloat16*)(ws);                 // 512x512  (N,K)
  __hip_bfloat16* W2T = (__hip_bfloat16*)(ws + 524288);        // 256x256
  __hip_bfloat16* W3T = (__hip_bfloat16*)(ws + 655360);        // 256x256
  __hip_bfloat16* W4T = (__hip_bfloat16*)(ws + 786432);        // 512x1024
  __hip_bfloat16* bufA = (__hip_bfloat16*)(ws + 2097152);      // 256 MB  (h0 / v3)
  __hip_bfloat16* bufB = bufA + (size_t)134217728;             // 256 MB  (v1 / h3)

  // weight prep (bf16 + transpose to (N,K))
  wtrans_kernel<<<(512 * 512) / 256, 256, 0, stream>>>(W1, W1T, 512, 512);
  wtrans_kernel<<<(256 * 256) / 256, 256, 0, stream>>>(W2, W2T, 256, 256);
  wtrans_kernel<<<(256 * 256) / 256, 256, 0, stream>>>(W3, W3T, 256, 256);
  wtrans_kernel<<<(1024 * 512) / 256, 256, 0, stream>>>(W4, W4T, 1024, 512);

  // sort: h0 = [x; sorted(x)] as (2B, 512) bf16 into bufA  (1 wave per row)
  sort_kernel<<<B / 4, 256, 0, stream>>>(x, bufA);

  // G1: (2B,512)@(512,512) -> perm-scatter -> v1 (B,1024) in bufB
  gemm_k<1, 512, 512><<<(2 * B / BM) * (512 / BN), 512, 0, stream>>>(bufA, W1T, bufB, nullptr, nullptr);
  // G2: (4B,256)@(256,256) -> perm-scatter -> v3 (B,1024) in bufA
  gemm_k<2, 256, 256><<<(4 * B / BM) * (256 / BN), 512, 0, stream>>>(bufB, W2T, bufA, nullptr, nullptr);
  // G3: (4B,256)@(256,256) + relu -> h3 (B,1024) in bufB
  gemm_k<3, 256, 256><<<(4 * B / BM) * (256 / BN), 512, 0, stream>>>(bufA, W3T, bufB, nullptr, nullptr);
  // G4: (B,1024)@(1024,512) + sigmoid * x -> out f32
  gemm_k<4, 512, 1024><<<(B / BM) * (512 / BN), 512, 0, stream>>>(bufB, W4T, nullptr, (float*)d_out, x);
}

// Round 7
// 1075.082 us; speedup vs baseline: 1.0594x; 1.0594x over previous
//
#include <hip/hip_runtime.h>
#include <hip/hip_bf16.h>
#include <cstdint>
#include <cstddef>

// ---------- types ----------
typedef short bf16x8 __attribute__((ext_vector_type(8)));   // 8 bf16 in 4 VGPRs
typedef float f32x4 __attribute__((ext_vector_type(4)));

// GEMM geometry: 128x256 tile, BK=64, 8 waves (2M x 4N), NBUF=3 ring.
// BN=256 (full-width for N=256 kernels, half for N=512) minimizes re-reads
// of the streaming A operand: the binding constraint is per-CU memory pace.
#define BM 128
#define BN 256
#define BK 64

// async global->LDS, 16B per lane. LDS dest is wave-uniform base; HW adds lane*16.
__device__ __forceinline__ void gl_lds16(const __hip_bfloat16* gp, __hip_bfloat16* lp) {
  __builtin_amdgcn_global_load_lds((const __attribute__((address_space(1))) void*)gp,
                                   (__attribute__((address_space(3))) void*)lp, 16, 0, 0);
}

// ---------- weight transpose + bf16 convert: dst[c*R + r] = src[r*C + c] ----------
__global__ void __launch_bounds__(256) wtrans_kernel(const float* __restrict__ src,
                                                     __hip_bfloat16* __restrict__ dst,
                                                     int R, int C) {
  int idx = blockIdx.x * 256 + threadIdx.x;
  if (idx >= R * C) return;
  int r = idx / C, c = idx % C;
  dst[(size_t)c * R + r] = __float2bfloat16(src[idx]);
}

// ---------- per-row sort: one WAVE per row, fully in-register bitonic ----------
__global__ void __launch_bounds__(256) sort_kernel(const float* __restrict__ x,
                                                   __hip_bfloat16* __restrict__ h0) {
  int row = blockIdx.x * 4 + (threadIdx.x >> 6);
  int lane = threadIdx.x & 63;
  const float* xr = x + (size_t)row * 512;

  float v[8];
  *(float4*)&v[0] = *(const float4*)&xr[lane * 8];
  *(float4*)&v[4] = *(const float4*)&xr[lane * 8 + 4];

  __hip_bfloat16* h = h0 + (size_t)row * 1024;
  {
    alignas(16) __hip_bfloat16 ob[8];
#pragma unroll
    for (int i = 0; i < 8; ++i) ob[i] = __float2bfloat16(v[i]);
    *(bf16x8*)&h[lane * 8] = *(const bf16x8*)ob;
  }

#pragma unroll
  for (int k = 2; k <= 512; k <<= 1) {
#pragma unroll
    for (int j = k >> 1; j > 0; j >>= 1) {
      if (j >= 8) {
        int L = j >> 3;
        bool lower = (lane & L) == 0;
        bool up = (((lane * 8) & k) == 0);
        bool sel = (lower == up);
#pragma unroll
        for (int r = 0; r < 8; ++r) {
          float pv = __shfl_xor(v[r], L, 64);
          float mn = fminf(v[r], pv), mx = fmaxf(v[r], pv);
          v[r] = sel ? mn : mx;
        }
      } else {
#pragma unroll
        for (int r = 0; r < 8; ++r) {
          if ((r & j) == 0) {
            int r2 = r | j;
            bool up = ((((lane * 8) + r) & k) == 0);
            float a = v[r], b = v[r2];
            float mn = fminf(a, b), mx = fmaxf(a, b);
            v[r] = up ? mn : mx;
            v[r2] = up ? mx : mn;
          }
        }
      }
    }
  }

  {
    alignas(16) __hip_bfloat16 ob[8];
#pragma unroll
    for (int i = 0; i < 8; ++i) ob[i] = __float2bfloat16(v[i]);
    *(bf16x8*)&h[512 + lane * 8] = *(const bf16x8*)ob;
  }
}

// ---------- GEMM: C(M,N) = A(M,K) @ BT(N,K)^T, bf16 in, f32 accum ----------
// 128x256 tile, BK=64, NBUF=3 ring, counted vmcnt(6), one barrier per K-tile.
// Staging: 6 gl_lds/thread/K-tile (A:2 chunks, B:4 chunks), pre-swizzled
// global source (8-slot XOR) -> 0 LDS bank conflicts (measured r5).
// Wave grid 2M x 4N, wave tile 64x64, acc[4][4].
// EPI: 1 = perm-scatter after G1; 2 = perm-scatter after G2; 3 = relu store;
//      4 = sigmoid(acc) * x, f32 store.
template <int EPI, int N, int K>
__global__ void __launch_bounds__(512) gemm_k(const __hip_bfloat16* __restrict__ A,
                                              const __hip_bfloat16* __restrict__ BT,
                                              __hip_bfloat16* __restrict__ Cb,
                                              float* __restrict__ Co,
                                              const float* __restrict__ X) {
  __shared__ __hip_bfloat16 lA[3][BM * BK];  // 3 x 16 KB
  __shared__ __hip_bfloat16 lB[3][BN * BK];  // 3 x 32 KB   (total 144 KB)

  // bijective XCD swizzle (grid divisible by 8)
  int nwg = gridDim.x;
  int bid = blockIdx.x;
  int cpx = nwg >> 3;
  int wg = (bid & 7) * cpx + (bid >> 3);

  constexpr int NTN = N / BN;  // 1 or 2
  int m0 = (wg / NTN) * BM;
  int n0 = (wg % NTN) * BN;

  int tid = threadIdx.x;
  int lane = tid & 63;
  int w = tid >> 6;        // 0..7
  int wr = w >> 2;         // 0..1 : wave's 64-row band
  int wc = w & 3;          // 0..3 : wave's 64-col band
  int r16 = lane & 15;
  int g4 = lane >> 4;      // 0..3

  // ---- staging lane geometry (pre-swizzled global source) ----
  int lr = lane >> 3;                      // 0..7 (row within 8-row chunk)
  int acs = 8 * ((lane & 7) ^ lr);         // swizzled col start (elems)
  const __hip_bfloat16* Asrc = A + (size_t)(m0 + w * 16 + lr) * K + acs;  // rows [16w,16w+16)
  const __hip_bfloat16* Bsrc = BT + (size_t)(n0 + w * 32 + lr) * K + acs; // rows [32w,32w+32)

  // ---- fragment read offsets (elems), swizzled ----
  int xorr = (r16 & 7) * 8;
  int arow[4], brow[4];
#pragma unroll
  for (int i = 0; i < 4; ++i) arow[i] = (wr * 64 + 16 * i + r16) * BK;
#pragma unroll
  for (int j = 0; j < 4; ++j) brow[j] = (wc * 64 + 16 * j + r16) * BK;
  int kx0 = (g4 * 8) ^ xorr;          // ks=0
  int kx1 = (32 + g4 * 8) ^ xorr;     // ks=1

  f32x4 acc[4][4] = {};

#define STAGE(tt)                                                         \
  do {                                                                    \
    const int k0_ = (tt) * BK, b_ = (tt) % 3;                             \
    gl_lds16(Asrc + k0_, &lA[b_][w * 1024]);                              \
    gl_lds16(Asrc + (size_t)8 * K + k0_, &lA[b_][w * 1024 + 512]);        \
    gl_lds16(Bsrc + k0_, &lB[b_][w * 2048]);                              \
    gl_lds16(Bsrc + (size_t)8 * K + k0_, &lB[b_][w * 2048 + 512]);        \
    gl_lds16(Bsrc + (size_t)16 * K + k0_, &lB[b_][w * 2048 + 1024]);      \
    gl_lds16(Bsrc + (size_t)24 * K + k0_, &lB[b_][w * 2048 + 1536]);      \
  } while (0)

  constexpr int NT = K / BK;  // 4, 8, or 16
  STAGE(0);
  STAGE(1);
  asm volatile("s_waitcnt vmcnt(6)" ::: "memory");  // tile 0 landed; tile 1 flying
  __builtin_amdgcn_s_barrier();

#pragma unroll
  for (int t = 0; t < NT; ++t) {
    const int cur = t % 3;

    if (t + 2 < NT) STAGE(t + 2);   // -> buf[(t+2)%3] = buf[(t-1)%3], free after barrier(t-1)

    // ks = 0 fragments
    bf16x8 a0[4], b0[4];
#pragma unroll
    for (int i = 0; i < 4; ++i) a0[i] = *(const bf16x8*)&lA[cur][arow[i] + kx0];
#pragma unroll
    for (int j = 0; j < 4; ++j) b0[j] = *(const bf16x8*)&lB[cur][brow[j] + kx0];

    __builtin_amdgcn_s_setprio(1);
#pragma unroll
    for (int i = 0; i < 4; ++i)
#pragma unroll
      for (int j = 0; j < 4; ++j)
        acc[i][j] = __builtin_amdgcn_mfma_f32_16x16x32_bf16(a0[i], b0[j], acc[i][j], 0, 0, 0);
    __builtin_amdgcn_s_setprio(0);

    // ks = 1 fragments
    bf16x8 a1[4], b1[4];
#pragma unroll
    for (int i = 0; i < 4; ++i) a1[i] = *(const bf16x8*)&lA[cur][arow[i] + kx1];
#pragma unroll
    for (int j = 0; j < 4; ++j) b1[j] = *(const bf16x8*)&lB[cur][brow[j] + kx1];

    __builtin_amdgcn_s_setprio(1);
#pragma unroll
    for (int i = 0; i < 4; ++i)
#pragma unroll
      for (int j = 0; j < 4; ++j)
        acc[i][j] = __builtin_amdgcn_mfma_f32_16x16x32_bf16(a1[i], b1[j], acc[i][j], 0, 0, 0);
    __builtin_amdgcn_s_setprio(0);

    if (t + 1 < NT) {
      if (t + 2 < NT) asm volatile("s_waitcnt vmcnt(6)" ::: "memory");  // t+1 landed
      else            asm volatile("s_waitcnt vmcnt(0)" ::: "memory");  // drain last
      __builtin_amdgcn_s_barrier();
    }
  }
#undef STAGE

  // epilogue: D row = g4*4 + r, col = r16 within each 16x16 frag (m89 layout)
#pragma unroll
  for (int i = 0; i < 4; ++i) {
    int grow_base = m0 + wr * 64 + 16 * i + g4 * 4;
#pragma unroll
    for (int j = 0; j < 4; ++j) {
      int gcol = n0 + wc * 64 + 16 * j + r16;
#pragma unroll
      for (int r = 0; r < 4; ++r) {
        int grow = grow_base + r;
        float v = acc[i][j][r];
        if constexpr (EPI == 1) {
          // v0 index j0 = p*512 + n -> dst col = 4*(n&255) + 2p + (n>>8)
          int b = grow >> 1, p = grow & 1;
          Cb[(size_t)b * 1024 + 4 * (gcol & 255) + (p << 1) + (gcol >> 8)] = __float2bfloat16(v);
        } else if constexpr (EPI == 2) {
          // h2 flat j0 = g*256 + n -> dst col = 4*n + g
          int b = grow >> 2, g = grow & 3;
          Cb[(size_t)b * 1024 + 4 * gcol + g] = __float2bfloat16(v);
        } else if constexpr (EPI == 3) {
          Cb[(size_t)grow * N + gcol] = __float2bfloat16(fmaxf(v, 0.f));
        } else {
          float xv = X[(size_t)grow * N + gcol];
          Co[(size_t)grow * N + gcol] = xv / (1.f + __expf(-v));
        }
      }
    }
  }
}

// ---------- launch ----------
extern "C" void kernel_launch(void* const* d_in, const int* in_sizes, int n_in,
                              void* d_out, int out_size, void* d_ws, size_t ws_size,
                              hipStream_t stream) {
  const float* x  = (const float*)d_in[0];
  const float* W1 = (const float*)d_in[1];
  const float* W2 = (const float*)d_in[2];
  const float* W3 = (const float*)d_in[3];
  const float* W4 = (const float*)d_in[4];

  const int B = 131072;

  char* ws = (char*)d_ws;
  __hip_bfloat16* W1T = (__hip_bfloat16*)(ws);                 // 512x512  (N,K)
  __hip_bfloat16* W2T = (__hip_bfloat16*)(ws + 524288);        // 256x256
  __hip_bfloat16* W3T = (__hip_bfloat16*)(ws + 655360);        // 256x256
  __hip_bfloat16* W4T = (__hip_bfloat16*)(ws + 786432);        // 512x1024
  __hip_bfloat16* bufA = (__hip_bfloat16*)(ws + 2097152);      // 256 MB  (h0 / v3)
  __hip_bfloat16* bufB = bufA + (size_t)134217728;             // 256 MB  (v1 / h3)

  // weight prep (bf16 + transpose to (N,K))
  wtrans_kernel<<<(512 * 512) / 256, 256, 0, stream>>>(W1, W1T, 512, 512);
  wtrans_kernel<<<(256 * 256) / 256, 256, 0, stream>>>(W2, W2T, 256, 256);
  wtrans_kernel<<<(256 * 256) / 256, 256, 0, stream>>>(W3, W3T, 256, 256);
  wtrans_kernel<<<(1024 * 512) / 256, 256, 0, stream>>>(W4, W4T, 1024, 512);

  // sort: h0 = [x; sorted(x)] as (2B, 512) bf16 into bufA  (1 wave per row)
  sort_kernel<<<B / 4, 256, 0, stream>>>(x, bufA);

  // G1: (2B,512)@(512,512) -> perm-scatter -> v1 (B,1024) in bufB
  gemm_k<1, 512, 512><<<(2 * B / BM) * (512 / BN), 512, 0, stream>>>(bufA, W1T, bufB, nullptr, nullptr);
  // G2: (4B,256)@(256,256) -> perm-scatter -> v3 (B,1024) in bufA
  gemm_k<2, 256, 256><<<(4 * B / BM) * (256 / BN), 512, 0, stream>>>(bufB, W2T, bufA, nullptr, nullptr);
  // G3: (4B,256)@(256,256) + relu -> h3 (B,1024) in bufB
  gemm_k<3, 256, 256><<<(4 * B / BM) * (256 / BN), 512, 0, stream>>>(bufA, W3T, bufB, nullptr, nullptr);
  // G4: (B,1024)@(1024,512) + sigmoid * x -> out f32
  gemm_k<4, 512, 1024><<<(B / BM) * (512 / BN), 512, 0, stream>>>(bufB, W4T, nullptr, (float*)d_out, x);
}